// Round 1
// baseline (1823.333 us; speedup 1.0000x reference)
//
#include <hip/hip_runtime.h>
#include <hip/hip_bf16.h>

#define B_  32
#define S_  1024
#define D_  512
#define H_  4
#define DH_ 384
#define FFN_ 2048

// ---------------------------------------------------------------------------
// Embedding + positional encoding: X[b,s,d] = emb[tok][d] + pos(s,d)
// ---------------------------------------------------------------------------
__global__ __launch_bounds__(256) void embed_pos_k(
    const int* __restrict__ inp, const float* __restrict__ emb,
    float* __restrict__ X)
{
    int idx = blockIdx.x * 256 + threadIdx.x;      // < 16777216
    int d  = idx & 511;
    int bs = idx >> 9;                              // b*1024+s
    int s  = bs & 1023;
    int tok = inp[bs];
    float e = emb[(long)tok * 512 + d];
    int j = d >> 1;
    float expo = (float)(2 * j) * (1.0f / 512.0f);
    float denom = powf(10000.0f, -expo);
    float ang = (float)s * denom;
    float pe = (d & 1) ? cosf(ang) : sinf(ang);
    X[idx] = e + pe;
}

// ---------------------------------------------------------------------------
// Weight repacks: Wp (H,D,384) -> WKV (D, H*256) [k|v parts], WQ (D, H*128)
// ---------------------------------------------------------------------------
__global__ __launch_bounds__(256) void repack_kv_k(
    const float* __restrict__ Wp, const float* __restrict__ bp,
    float* __restrict__ WKV, float* __restrict__ BKV)
{
    int i = blockIdx.x * 256 + threadIdx.x;        // < 524288
    int d = i >> 10;
    int r = i & 1023;
    int h = r >> 8;
    int j = r & 255;
    WKV[i] = Wp[((long)h * 512 + d) * 384 + 128 + j];
    if (i < 1024) {
        int hh = i >> 8, jj = i & 255;
        BKV[i] = bp[hh * 384 + 128 + jj];
    }
}

__global__ __launch_bounds__(256) void repack_q_k(
    const float* __restrict__ Wp, const float* __restrict__ bp,
    float* __restrict__ WQ, float* __restrict__ BQ)
{
    int i = blockIdx.x * 256 + threadIdx.x;        // < 262144
    int d = i >> 9;
    int r = i & 511;
    int h = r >> 7;
    int e = r & 127;
    WQ[i] = Wp[((long)h * 512 + d) * 384 + e];
    if (i < 512) {
        int hh = i >> 7, ee = i & 127;
        BQ[i] = bp[hh * 384 + ee];
    }
}

// ---------------------------------------------------------------------------
// Generic fp32 tiled GEMM.  C = ACT(alpha*(op(A)@B) + bias)
// TA=false: A[m*lda + k];  TA=true: A[k*lda + m]
// batched via blockIdx.z -> (zb = z/subH, zh = z%subH) pointer offsets.
// ---------------------------------------------------------------------------
template<bool TA, int ACT>
__global__ __launch_bounds__(256) void gemm_f32(
    const float* __restrict__ A, const float* __restrict__ Bm,
    const float* __restrict__ bias, float* __restrict__ C,
    int M, int N, int K, int lda, int ldb, int ldc, float alpha,
    long aOffB, long aOffH, long bOffB, long bOffH, long cOffB, long cOffH,
    int subH)
{
    constexpr int BM = 64, BN = 64, BK = 16;
    __shared__ float As[BK][BM + 1];
    __shared__ float Bs[BK][BN + 1];

    int z  = blockIdx.z;
    int zb = z / subH, zh = z - zb * subH;
    A  += (long)zb * aOffB + (long)zh * aOffH;
    Bm += (long)zb * bOffB + (long)zh * bOffH;
    C  += (long)zb * cOffB + (long)zh * cOffH;

    int tid = threadIdx.x;
    int bm = blockIdx.y * BM, bn = blockIdx.x * BN;
    int tm = (tid >> 4) << 2;      // [0,64) step 4
    int tn = (tid & 15) << 2;      // [0,64) step 4
    float acc[4][4] = {};

    for (int k0 = 0; k0 < K; k0 += BK) {
#pragma unroll
        for (int t = 0; t < 4; t++) {
            int i = tid + t * 256;
            if (TA) {
                int m = i & 63, kk = i >> 6;
                int gm = bm + m;
                As[kk][m] = (gm < M) ? A[(long)(k0 + kk) * lda + gm] : 0.f;
            } else {
                int m = i >> 4, kk = i & 15;
                int gm = bm + m;
                As[kk][m] = (gm < M) ? A[(long)gm * lda + (k0 + kk)] : 0.f;
            }
            int n = i & 63, kk2 = i >> 6;
            int gn = bn + n;
            Bs[kk2][n] = (gn < N) ? Bm[(long)(k0 + kk2) * ldb + gn] : 0.f;
        }
        __syncthreads();
#pragma unroll
        for (int kk = 0; kk < BK; kk++) {
            float a[4], bb[4];
#pragma unroll
            for (int i = 0; i < 4; i++) a[i] = As[kk][tm + i];
#pragma unroll
            for (int j = 0; j < 4; j++) bb[j] = Bs[kk][tn + j];
#pragma unroll
            for (int i = 0; i < 4; i++)
#pragma unroll
                for (int j = 0; j < 4; j++)
                    acc[i][j] += a[i] * bb[j];
        }
        __syncthreads();
    }

#pragma unroll
    for (int i = 0; i < 4; i++) {
        int gm = bm + tm + i;
        if (gm >= M) continue;
#pragma unroll
        for (int j = 0; j < 4; j++) {
            int gn = bn + tn + j;
            if (gn >= N) continue;
            float v = alpha * acc[i][j] + (bias ? bias[gn] : 0.f);
            if (ACT == 1) v = fmaxf(v, 0.f);
            C[(long)gm * ldc + gn] = v;
        }
    }
}

// ---------------------------------------------------------------------------
// heads0: concat0[b, h*128+e] = sum_f q0[b,h*128+f] * KV[b,h,f,e]
// (scale already folded into KV via alpha)
// ---------------------------------------------------------------------------
__global__ __launch_bounds__(512) void heads0_k(
    const float* __restrict__ q0, const float* __restrict__ kv,
    float* __restrict__ c0)
{
    int b = blockIdx.x;
    int j = threadIdx.x;                 // 512 threads
    int h = j >> 7, e = j & 127;
    const float* qp  = q0 + b * 512 + h * 128;
    const float* kvp = kv + ((long)(b * 4 + h) * 128) * 128 + e;
    float acc = 0.f;
#pragma unroll 8
    for (int f = 0; f < 128; f++) acc += qp[f] * kvp[(long)f * 128];
    c0[b * 512 + j] = acc;
}

// ---------------------------------------------------------------------------
// Row LayerNorm over D=512 with residual:  out = LN(in + res)*g + b
// ---------------------------------------------------------------------------
__global__ __launch_bounds__(256) void ln_rows_k(
    const float* __restrict__ in, const float* __restrict__ res,
    long resStride, const float* __restrict__ g, const float* __restrict__ bta,
    float* __restrict__ out)
{
    int b = blockIdx.x;
    int t = threadIdx.x;
    float a0 = in[b * 512 + t]       + res[(long)b * resStride + t];
    float a1 = in[b * 512 + t + 256] + res[(long)b * resStride + t + 256];

    __shared__ float sd[8];
    float s = a0 + a1;
#pragma unroll
    for (int off = 32; off; off >>= 1) s += __shfl_down(s, off, 64);
    if ((t & 63) == 0) sd[t >> 6] = s;
    __syncthreads();
    float mean = (sd[0] + sd[1] + sd[2] + sd[3]) * (1.0f / 512.0f);

    float d0 = a0 - mean, d1 = a1 - mean;
    float v = d0 * d0 + d1 * d1;
#pragma unroll
    for (int off = 32; off; off >>= 1) v += __shfl_down(v, off, 64);
    if ((t & 63) == 0) sd[4 + (t >> 6)] = v;
    __syncthreads();
    float var = (sd[4] + sd[5] + sd[6] + sd[7]) * (1.0f / 512.0f);
    float rs = rsqrtf(var + 0.001f);

    out[b * 512 + t]       = d0 * rs * g[t]       + bta[t];
    out[b * 512 + t + 256] = d1 * rs * g[t + 256] + bta[t + 256];
}

// ---------------------------------------------------------------------------
// Final head: hid = relu(x2 @ Wh + bh); logit = hid @ Wf + bf; out + sigmoid
// ---------------------------------------------------------------------------
__global__ __launch_bounds__(256) void head_k(
    const float* __restrict__ x2, const float* __restrict__ Wh,
    const float* __restrict__ bh, const float* __restrict__ Wf,
    const float* __restrict__ bf, float* __restrict__ out)
{
    int b = blockIdx.x;
    int t = threadIdx.x;
    __shared__ float xs[512];
    xs[t]       = x2[b * 512 + t];
    xs[t + 256] = x2[b * 512 + t + 256];
    __syncthreads();

    float p = 0.f;
#pragma unroll
    for (int rep = 0; rep < 2; rep++) {
        int j = t + rep * 256;
        float acc = bh[j];
        for (int d = 0; d < 512; d++) acc += xs[d] * Wh[(long)d * 512 + j];
        p += fmaxf(acc, 0.f) * Wf[j];
    }
    __shared__ float sd[4];
#pragma unroll
    for (int off = 32; off; off >>= 1) p += __shfl_down(p, off, 64);
    if ((t & 63) == 0) sd[t >> 6] = p;
    __syncthreads();
    if (t == 0) {
        float logit = sd[0] + sd[1] + sd[2] + sd[3] + bf[0];
        out[b]      = logit;
        out[32 + b] = 1.f / (1.f + expf(-logit));
    }
}

// ---------------------------------------------------------------------------
extern "C" void kernel_launch(void* const* d_in, const int* in_sizes, int n_in,
                              void* d_out, int out_size, void* d_ws, size_t ws_size,
                              hipStream_t stream)
{
    const int*   inputs = (const int*)  d_in[0];
    const float* emb    = (const float*)d_in[1];
    const float* Wp     = (const float*)d_in[2];
    const float* bp     = (const float*)d_in[3];
    const float* Wo     = (const float*)d_in[4];
    const float* bo     = (const float*)d_in[5];
    const float* ln1_g  = (const float*)d_in[6];
    const float* ln1_b  = (const float*)d_in[7];
    const float* W1     = (const float*)d_in[8];
    const float* b1     = (const float*)d_in[9];
    const float* W2     = (const float*)d_in[10];
    const float* b2     = (const float*)d_in[11];
    const float* ln2_g  = (const float*)d_in[12];
    const float* ln2_b  = (const float*)d_in[13];
    const float* Wh     = (const float*)d_in[14];
    const float* bh     = (const float*)d_in[15];
    const float* Wf     = (const float*)d_in[16];
    const float* bf     = (const float*)d_in[17];
    float* out = (float*)d_out;

    // workspace layout (floats)
    float* X    = (float*)d_ws;                 // 16,777,216  (B,S,D)
    float* KVP  = X    + 16777216;              // 33,554,432  (B,S,H,256) [k|v]
    float* KV   = KVP  + 33554432;              //  2,097,152  (B,H,128,128)
    float* WKV  = KV   + 2097152;               //    524,288  (D, H*256)
    float* WQ   = WKV  + 524288;                //    262,144  (D, H*128)
    float* BKV  = WQ   + 262144;                //      1,024
    float* BQ   = BKV  + 1024;                  //        512
    float* Q0   = BQ   + 512;                   //     16,384  (32,512)
    float* C0   = Q0   + 16384;                 //     16,384
    float* ATT0 = C0   + 16384;                 //     16,384
    float* Y1   = ATT0 + 16384;                 //     16,384
    float* H1b  = Y1   + 16384;                 //     65,536  (32,2048)
    float* H2b  = H1b  + 65536;                 //     16,384
    float* X2   = H2b  + 16384;                 //     16,384

    // 1) embedding + positional encoding (full B*S rows: k,v need all of X)
    embed_pos_k<<<65536, 256, 0, stream>>>(inputs, emb, X);

    // 2) weight repacks
    repack_kv_k<<<524288 / 256, 256, 0, stream>>>(Wp, bp, WKV, BKV);
    repack_q_k <<<262144 / 256, 256, 0, stream>>>(Wp, bp, WQ, BQ);

    // 3) k,v projection for ALL rows: KVP = X @ WKV + BKV   (M=32768,N=1024,K=512)
    gemm_f32<false, 0><<<dim3(1024 / 64, 32768 / 64, 1), 256, 0, stream>>>(
        X, WKV, BKV, KVP, 32768, 1024, 512, 512, 1024, 1024, 1.0f,
        0, 0, 0, 0, 0, 0, 1);

    // 4) KV[b,h,f,e] = scale * sum_s k[b,s,h,f] * v[b,s,h,e]  (TA GEMM, batched)
    gemm_f32<true, 0><<<dim3(2, 2, B_ * H_), 256, 0, stream>>>(
        KVP, KVP + 128, nullptr, KV, 128, 128, 1024, 1024, 1024, 128,
        0.03125f /* 1/sqrt(1024) */,
        (long)S_ * 1024, 256, (long)S_ * 1024, 256, (long)H_ * 16384, 16384, H_);

    // 5) q at s=0 only: Q0 = X[:,0,:] @ WQ + BQ   (M=32,N=512,K=512)
    gemm_f32<false, 0><<<dim3(8, 1, 1), 256, 0, stream>>>(
        X, WQ, BQ, Q0, 32, 512, 512, S_ * D_, 512, 512, 1.0f,
        0, 0, 0, 0, 0, 0, 1);

    // 6) heads at s=0: concat0 = q0 @ KV (scale already in KV)
    heads0_k<<<32, 512, 0, stream>>>(Q0, KV, C0);

    // 7) attn0 = concat0 @ Wo + bo
    gemm_f32<false, 0><<<dim3(8, 1, 1), 256, 0, stream>>>(
        C0, Wo, bo, ATT0, 32, 512, 512, 512, 512, 512, 1.0f,
        0, 0, 0, 0, 0, 0, 1);

    // 8) Y1 = LN(attn0 + X[:,0,:])
    ln_rows_k<<<32, 256, 0, stream>>>(ATT0, X, (long)S_ * D_, ln1_g, ln1_b, Y1);

    // 9) FFN on 32 rows: H1 = relu(Y1 @ W1 + b1); H2 = H1 @ W2 + b2
    gemm_f32<false, 1><<<dim3(32, 1, 1), 256, 0, stream>>>(
        Y1, W1, b1, H1b, 32, 2048, 512, 512, 2048, 2048, 1.0f,
        0, 0, 0, 0, 0, 0, 1);
    gemm_f32<false, 0><<<dim3(8, 1, 1), 256, 0, stream>>>(
        H1b, W2, b2, H2b, 32, 512, 2048, 2048, 512, 512, 1.0f,
        0, 0, 0, 0, 0, 0, 1);

    // 10) X2 = LN(H2 + Y1)
    ln_rows_k<<<32, 256, 0, stream>>>(H2b, Y1, 512, ln2_g, ln2_b, X2);

    // 11) final head -> logits + sigmoid
    head_k<<<32, 256, 0, stream>>>(X2, Wh, bh, Wf, bf, out);
}

// Round 2
// 1033.466 us; speedup vs baseline: 1.7643x; 1.7643x over previous
//
#include <hip/hip_runtime.h>
#include <hip/hip_bf16.h>

typedef unsigned short ushort_t;
typedef __attribute__((ext_vector_type(8))) short short8;
typedef __attribute__((ext_vector_type(4))) float floatx4;

// ---------------------------------------------------------------------------
// helpers
// ---------------------------------------------------------------------------
__device__ inline void gll16(const void* g, void* l) {
    __builtin_amdgcn_global_load_lds(
        (const __attribute__((address_space(1))) unsigned int*)g,
        (__attribute__((address_space(3))) unsigned int*)l, 16, 0, 0);
}
__device__ inline ushort_t f2bf(float x) {
    unsigned u = __float_as_uint(x);
    return (ushort_t)((u + 0x7FFFu + ((u >> 16) & 1u)) >> 16);
}
__device__ inline float bf2f(ushort_t u) { return __uint_as_float((unsigned)u << 16); }

// ---------------------------------------------------------------------------
// Positional-encoding table PE[s][d], fp32 (1024 x 512)
// ---------------------------------------------------------------------------
__global__ __launch_bounds__(256) void pe_k(float* __restrict__ PE)
{
    int idx = blockIdx.x * 256 + threadIdx.x;      // < 524288
    int d = idx & 511, s = idx >> 9;
    float expo = (float)(d & ~1) * (1.0f / 512.0f);
    float ang = (float)s * exp2f(-expo * 13.287712379549449f); // 10000^-expo
    PE[idx] = (d & 1) ? cosf(ang) : sinf(ang);
}

// ---------------------------------------------------------------------------
// Embedding + PE, transposed output: Xt[b][d][s] (bf16), X0[b][d] fp32 (s=0)
// Per block: 64s x 64d tile, LDS transpose, coalesced 16B writes.
// ---------------------------------------------------------------------------
__global__ __launch_bounds__(256) void embed_k(
    const int* __restrict__ inp, const float* __restrict__ emb,
    const float* __restrict__ PE, ushort_t* __restrict__ Xt,
    float* __restrict__ X0)
{
    __shared__ int toks[64];
    __shared__ ushort_t tile[64][65];   // [d_local][s_local], padded
    int b = blockIdx.z, s0 = blockIdx.y * 64, d0 = blockIdx.x * 64;
    int t = threadIdx.x;
    if (t < 64) toks[t] = inp[b * 1024 + s0 + t];
    __syncthreads();

    int sl = t >> 2, c = t & 3;
    int s = s0 + sl;
    long ebase = (long)toks[sl] * 512 + d0 + c * 16;
    long pbase = (long)s * 512 + d0 + c * 16;
#pragma unroll
    for (int i = 0; i < 4; i++) {
        float4 e4 = *(const float4*)&emb[ebase + i * 4];
        float4 p4 = *(const float4*)&PE[pbase + i * 4];
        float v0 = e4.x + p4.x, v1 = e4.y + p4.y, v2 = e4.z + p4.z, v3 = e4.w + p4.w;
        int dl = c * 16 + i * 4;
        tile[dl + 0][sl] = f2bf(v0);
        tile[dl + 1][sl] = f2bf(v1);
        tile[dl + 2][sl] = f2bf(v2);
        tile[dl + 3][sl] = f2bf(v3);
        if (s == 0)
            *(float4*)&X0[b * 512 + d0 + dl] = make_float4(v0, v1, v2, v3);
    }
    __syncthreads();

    int dl = t >> 2, cc = t & 3;
    unsigned pk[8];
#pragma unroll
    for (int k = 0; k < 8; k++) {
        unsigned lo = tile[dl][cc * 16 + k * 2];
        unsigned hi = tile[dl][cc * 16 + k * 2 + 1];
        pk[k] = lo | (hi << 16);
    }
    uint4* dst = (uint4*)(Xt + ((long)(b * 512 + d0 + dl)) * 1024 + s0 + cc * 16);
    dst[0] = make_uint4(pk[0], pk[1], pk[2], pk[3]);
    dst[1] = make_uint4(pk[4], pk[5], pk[6], pk[7]);
}

// ---------------------------------------------------------------------------
// Column sums cs[b][d] = sum_s X[b,s,d]  (reads Xt rows, coalesced)
// ---------------------------------------------------------------------------
__global__ __launch_bounds__(256) void cs_k(
    const ushort_t* __restrict__ Xt, float* __restrict__ cs)
{
    int b = blockIdx.x, d0 = blockIdx.y * 64;
    int t = threadIdx.x, wave = t >> 6, lane = t & 63;
#pragma unroll 1
    for (int it = 0; it < 16; it++) {
        int d = d0 + it * 4 + wave;
        const uint4* row = (const uint4*)(Xt + ((long)(b * 512 + d)) * 1024);
        uint4 v0 = row[lane * 2], v1 = row[lane * 2 + 1];
        float s = 0.f;
        s += bf2f(v0.x & 0xffff) + bf2f(v0.x >> 16);
        s += bf2f(v0.y & 0xffff) + bf2f(v0.y >> 16);
        s += bf2f(v0.z & 0xffff) + bf2f(v0.z >> 16);
        s += bf2f(v0.w & 0xffff) + bf2f(v0.w >> 16);
        s += bf2f(v1.x & 0xffff) + bf2f(v1.x >> 16);
        s += bf2f(v1.y & 0xffff) + bf2f(v1.y >> 16);
        s += bf2f(v1.z & 0xffff) + bf2f(v1.z >> 16);
        s += bf2f(v1.w & 0xffff) + bf2f(v1.w >> 16);
#pragma unroll
        for (int off = 32; off; off >>= 1) s += __shfl_down(s, off);
        if (lane == 0) cs[b * 512 + d] = s;
    }
}

// ---------------------------------------------------------------------------
// Gram: G[b] = Xb^T Xb  (512x512, K=S=1024), bf16 MFMA 16x16x32.
// 128x128 tile/block, global_load_lds(16B) staging, XOR-swizzled LDS.
// ---------------------------------------------------------------------------
__global__ __launch_bounds__(256) void gram_k(
    const ushort_t* __restrict__ Xt, float* __restrict__ G)
{
    __shared__ __align__(16) ushort_t As[4096];   // [128 rows][32 s] swizzled
    __shared__ __align__(16) ushort_t Bs[4096];
    int b = blockIdx.z;
    int bm = blockIdx.y * 128, bn = blockIdx.x * 128;
    const ushort_t* Xb = Xt + (long)b * 524288;
    int t = threadIdx.x, wave = t >> 6, lane = t & 63;
    int wm = (wave >> 1) * 64, wn = (wave & 1) * 64;

    floatx4 acc[4][4];
#pragma unroll
    for (int i = 0; i < 4; i++)
#pragma unroll
        for (int j = 0; j < 4; j++) acc[i][j] = 0.0f;

    int rlo = lane >> 2;          // 0..15
    int craw = lane & 3;          // 16B chunk slot within 64B row

    for (int k0 = 0; k0 < 1024; k0 += 32) {
        __syncthreads();
#pragma unroll
        for (int cchunk = 0; cchunk < 2; cchunk++) {
            int ch = wave * 2 + cchunk;           // 0..7
            int rowl = ch * 16 + rlo;             // local row 0..127
            int cA = craw ^ ((rowl >> 1) & 3);    // swizzled source chunk
            gll16(Xb + (long)(bm + rowl) * 1024 + k0 + cA * 8,
                  (char*)As + ch * 1024);
            gll16(Xb + (long)(bn + rowl) * 1024 + k0 + cA * 8,
                  (char*)Bs + ch * 1024);
        }
        __builtin_amdgcn_s_waitcnt(0);
        __syncthreads();

        short8 a[4], bb[4];
        int m16 = lane & 15, kq = lane >> 4;
#pragma unroll
        for (int i = 0; i < 4; i++) {
            int row = wm + i * 16 + m16;
            int c16 = kq ^ ((row >> 1) & 3);
            a[i] = *(const short8*)&As[row * 32 + c16 * 8];
            int rowb = wn + i * 16 + m16;
            int c16b = kq ^ ((rowb >> 1) & 3);
            bb[i] = *(const short8*)&Bs[rowb * 32 + c16b * 8];
        }
#pragma unroll
        for (int i = 0; i < 4; i++)
#pragma unroll
            for (int j = 0; j < 4; j++)
                acc[i][j] = __builtin_amdgcn_mfma_f32_16x16x32_bf16(
                    a[i], bb[j], acc[i][j], 0, 0, 0);
    }

    float* Gb = G + (long)b * 262144;
    int n0 = lane & 15, r0 = (lane >> 4) * 4;
#pragma unroll
    for (int i = 0; i < 4; i++)
#pragma unroll
        for (int j = 0; j < 4; j++)
#pragma unroll
            for (int reg = 0; reg < 4; reg++) {
                int m = bm + wm + i * 16 + r0 + reg;
                int n = bn + wn + j * 16 + n0;
                Gb[(long)m * 512 + n] = acc[i][j][reg];
            }
}

// ---------------------------------------------------------------------------
// q0[b][h*128+f] = X0[b] . Wp[h][:,f] + bp[h][f]
// ---------------------------------------------------------------------------
__global__ __launch_bounds__(256) void q0_k(
    const float* __restrict__ X0, const float* __restrict__ Wp,
    const float* __restrict__ bp, float* __restrict__ Q0)
{
    __shared__ float xs[512];
    int b = blockIdx.x, t = threadIdx.x;
    xs[t] = X0[b * 512 + t];
    xs[t + 256] = X0[b * 512 + t + 256];
    __syncthreads();
#pragma unroll
    for (int rep = 0; rep < 2; rep++) {
        int j = t + rep * 256;
        int h = j >> 7, f = j & 127;
        float acc = bp[h * 384 + f];
        for (int d = 0; d < 512; d++)
            acc += xs[d] * Wp[((long)(h * 512 + d)) * 384 + f];
        Q0[b * 512 + j] = acc;
    }
}

// ---------------------------------------------------------------------------
// r[b,h,d] = sum_f q0[b,h,f] * Wk[h][d][f];  alpha[b,h] = q0 . bk[h]
// (Wk = Wp[...,128:256], bk = bp[...,128:256])
// ---------------------------------------------------------------------------
__global__ __launch_bounds__(256) void r_k(
    const float* __restrict__ Q0, const float* __restrict__ Wp,
    const float* __restrict__ bp, float* __restrict__ r,
    float* __restrict__ alpha)
{
    __shared__ float q[128];
    __shared__ float red[128];
    int bh = blockIdx.x, b = bh >> 2, h = bh & 3;
    int t = threadIdx.x;
    if (t < 128) q[t] = Q0[b * 512 + h * 128 + t];
    __syncthreads();
    if (t < 128) red[t] = q[t] * bp[h * 384 + 128 + t];
    __syncthreads();
    for (int w = 64; w >= 1; w >>= 1) {
        if (t < w) red[t] += red[t + w];
        __syncthreads();
    }
    if (t == 0) alpha[bh] = red[0];

    const float4* q4 = (const float4*)q;
#pragma unroll
    for (int rep = 0; rep < 2; rep++) {
        int d = t + rep * 256;
        const float4* wrow = (const float4*)&Wp[((long)(h * 512 + d)) * 384 + 128];
        float acc = 0.f;
#pragma unroll 8
        for (int f4 = 0; f4 < 32; f4++) {
            float4 w = wrow[f4], qq = q4[f4];
            acc += w.x * qq.x + w.y * qq.y + w.z * qq.z + w.w * qq.w;
        }
        r[(long)bh * 512 + d] = acc;
    }
}

// ---------------------------------------------------------------------------
// t'[b,h,d2] = sum_d1 r[b,h,d1]*G[b][d1,d2] + alpha*cs[b,d2]
// gamma[b,h]  = r.cs + 1024*alpha
// One block per b (all 4 heads share the G read).
// ---------------------------------------------------------------------------
__global__ __launch_bounds__(256) void t_k(
    const float* __restrict__ r, const float* __restrict__ G,
    const float* __restrict__ cs, const float* __restrict__ alpha,
    float* __restrict__ Tp, float* __restrict__ gamma)
{
    __shared__ float rs[2048];
    __shared__ float csb[512];
    __shared__ float alf[4];
    __shared__ float red[256];
    int b = blockIdx.x, t = threadIdx.x;
#pragma unroll
    for (int i = 0; i < 8; i++) rs[t + i * 256] = r[(long)b * 2048 + t + i * 256];
    csb[t] = cs[b * 512 + t];
    csb[t + 256] = cs[b * 512 + t + 256];
    if (t < 4) alf[t] = alpha[b * 4 + t];
    __syncthreads();

    float acc[8] = {0, 0, 0, 0, 0, 0, 0, 0};
    const float* Gb = G + (long)b * 262144;
    for (int d1 = 0; d1 < 512; d1++) {
        float g0 = Gb[(long)d1 * 512 + t];
        float g1 = Gb[(long)d1 * 512 + t + 256];
#pragma unroll
        for (int hh = 0; hh < 4; hh++) {
            float rr = rs[hh * 512 + d1];
            acc[hh * 2] += rr * g0;
            acc[hh * 2 + 1] += rr * g1;
        }
    }
#pragma unroll
    for (int hh = 0; hh < 4; hh++) {
        Tp[((long)(b * 4 + hh)) * 512 + t] = acc[hh * 2] + alf[hh] * csb[t];
        Tp[((long)(b * 4 + hh)) * 512 + t + 256] = acc[hh * 2 + 1] + alf[hh] * csb[t + 256];
    }
    for (int hh = 0; hh < 4; hh++) {
        red[t] = rs[hh * 512 + t] * csb[t] + rs[hh * 512 + t + 256] * csb[t + 256];
        __syncthreads();
        for (int w = 128; w >= 1; w >>= 1) {
            if (t < w) red[t] += red[t + w];
            __syncthreads();
        }
        if (t == 0) gamma[b * 4 + hh] = red[0] + 1024.0f * alf[hh];
        __syncthreads();
    }
}

// ---------------------------------------------------------------------------
// heads0 -> @Wo -> +res -> LN1, one block per b.
// c0[j] = scale*( sum_d t'[h][d]*Wv[h][d][e] + gamma[h]*bv[h][e] ), j=h*128+e
// Y1 = LN(c0@Wo + bo + X0)
// ---------------------------------------------------------------------------
__global__ __launch_bounds__(256) void hw_k(
    const float* __restrict__ Tp, const float* __restrict__ gamma,
    const float* __restrict__ Wp, const float* __restrict__ bp,
    const float* __restrict__ Wo, const float* __restrict__ bo,
    const float* __restrict__ X0, const float* __restrict__ g1,
    const float* __restrict__ b1v, float* __restrict__ Y1)
{
    __shared__ float tp[2048];
    __shared__ float c0s[512];
    __shared__ float gam[4];
    __shared__ float sd[8];
    int b = blockIdx.x, t = threadIdx.x;
#pragma unroll
    for (int i = 0; i < 8; i++) tp[t + i * 256] = Tp[(long)b * 2048 + t + i * 256];
    if (t < 4) gam[t] = gamma[b * 4 + t];
    __syncthreads();

#pragma unroll
    for (int rep = 0; rep < 2; rep++) {
        int j = t + rep * 256;
        int h = j >> 7, e = j & 127;
        float acc = gam[h] * bp[h * 384 + 256 + e];
        const float* tph = &tp[h * 512];
        for (int d = 0; d < 512; d++)
            acc += tph[d] * Wp[((long)(h * 512 + d)) * 384 + 256 + e];
        c0s[j] = 0.03125f * acc;
    }
    __syncthreads();

    float a01[2];
#pragma unroll
    for (int rep = 0; rep < 2; rep++) {
        int j = t + rep * 256;
        float acc = bo[j];
        for (int d = 0; d < 512; d++) acc += c0s[d] * Wo[(long)d * 512 + j];
        a01[rep] = acc + X0[b * 512 + j];
    }
    float a0 = a01[0], a1 = a01[1];

    float s = a0 + a1;
#pragma unroll
    for (int off = 32; off; off >>= 1) s += __shfl_down(s, off);
    if ((t & 63) == 0) sd[t >> 6] = s;
    __syncthreads();
    float mean = (sd[0] + sd[1] + sd[2] + sd[3]) * (1.0f / 512.0f);
    float d0 = a0 - mean, d1 = a1 - mean;
    float v = d0 * d0 + d1 * d1;
#pragma unroll
    for (int off = 32; off; off >>= 1) v += __shfl_down(v, off);
    if ((t & 63) == 0) sd[4 + (t >> 6)] = v;
    __syncthreads();
    float var = (sd[4] + sd[5] + sd[6] + sd[7]) * (1.0f / 512.0f);
    float rstd = rsqrtf(var + 0.001f);
    Y1[b * 512 + t] = d0 * rstd * g1[t] + b1v[t];
    Y1[b * 512 + t + 256] = d1 * rstd * g1[t + 256] + b1v[t + 256];
}

// ---------------------------------------------------------------------------
// Skinny GEMM for the 32-row FFN: out[32,N] = ACT(A[32,K] @ W[K,N] + bias)
// One block per 64 columns; all 32 rows per block (W read exactly once).
// ---------------------------------------------------------------------------
template<int ACT>
__global__ __launch_bounds__(256) void tailmm_k(
    const float* __restrict__ A, const float* __restrict__ W,
    const float* __restrict__ bias, float* __restrict__ out, int K, int N)
{
    __shared__ float at[32][64];
    int t = threadIdx.x;
    int j = blockIdx.x * 64 + (t & 63);
    int rg = t >> 6;
    float acc[8] = {0, 0, 0, 0, 0, 0, 0, 0};
    for (int k0 = 0; k0 < K; k0 += 64) {
        __syncthreads();
        {
            int rr = t >> 3, dd = (t & 7) * 8;
            float4 v0 = *(const float4*)&A[(long)rr * K + k0 + dd];
            float4 v1 = *(const float4*)&A[(long)rr * K + k0 + dd + 4];
            *(float4*)&at[rr][dd] = v0;
            *(float4*)&at[rr][dd + 4] = v1;
        }
        __syncthreads();
        for (int d = 0; d < 64; d++) {
            float w = W[(long)(k0 + d) * N + j];
#pragma unroll
            for (int rr2 = 0; rr2 < 8; rr2++)
                acc[rr2] += at[rg * 8 + rr2][d] * w;
        }
    }
#pragma unroll
    for (int rr2 = 0; rr2 < 8; rr2++) {
        float val = acc[rr2] + bias[j];
        if (ACT) val = fmaxf(val, 0.f);
        out[(long)(rg * 8 + rr2) * N + j] = val;
    }
}

// ---------------------------------------------------------------------------
// Row LayerNorm over D=512 with residual:  out = LN(in + res)*g + b
// ---------------------------------------------------------------------------
__global__ __launch_bounds__(256) void ln_rows_k(
    const float* __restrict__ in, const float* __restrict__ res,
    long resStride, const float* __restrict__ g, const float* __restrict__ bta,
    float* __restrict__ out)
{
    int b = blockIdx.x;
    int t = threadIdx.x;
    float a0 = in[b * 512 + t] + res[(long)b * resStride + t];
    float a1 = in[b * 512 + t + 256] + res[(long)b * resStride + t + 256];

    __shared__ float sd[8];
    float s = a0 + a1;
#pragma unroll
    for (int off = 32; off; off >>= 1) s += __shfl_down(s, off);
    if ((t & 63) == 0) sd[t >> 6] = s;
    __syncthreads();
    float mean = (sd[0] + sd[1] + sd[2] + sd[3]) * (1.0f / 512.0f);

    float d0 = a0 - mean, d1 = a1 - mean;
    float v = d0 * d0 + d1 * d1;
#pragma unroll
    for (int off = 32; off; off >>= 1) v += __shfl_down(v, off);
    if ((t & 63) == 0) sd[4 + (t >> 6)] = v;
    __syncthreads();
    float var = (sd[4] + sd[5] + sd[6] + sd[7]) * (1.0f / 512.0f);
    float rstd = rsqrtf(var + 0.001f);

    out[b * 512 + t] = d0 * rstd * g[t] + bta[t];
    out[b * 512 + t + 256] = d1 * rstd * g[t + 256] + bta[t + 256];
}

// ---------------------------------------------------------------------------
// Final head: hid = relu(x2 @ Wh + bh); logit = hid @ Wf + bf; out + sigmoid
// ---------------------------------------------------------------------------
__global__ __launch_bounds__(256) void head_k(
    const float* __restrict__ x2, const float* __restrict__ Wh,
    const float* __restrict__ bh, const float* __restrict__ Wf,
    const float* __restrict__ bf, float* __restrict__ out)
{
    int b = blockIdx.x;
    int t = threadIdx.x;
    __shared__ float xs[512];
    __shared__ float sd[4];
    xs[t] = x2[b * 512 + t];
    xs[t + 256] = x2[b * 512 + t + 256];
    __syncthreads();

    float p = 0.f;
#pragma unroll
    for (int rep = 0; rep < 2; rep++) {
        int j = t + rep * 256;
        float acc = bh[j];
        for (int d = 0; d < 512; d++) acc += xs[d] * Wh[(long)d * 512 + j];
        p += fmaxf(acc, 0.f) * Wf[j];
    }
#pragma unroll
    for (int off = 32; off; off >>= 1) p += __shfl_down(p, off);
    if ((t & 63) == 0) sd[t >> 6] = p;
    __syncthreads();
    if (t == 0) {
        float logit = sd[0] + sd[1] + sd[2] + sd[3] + bf[0];
        out[b] = logit;
        out[32 + b] = 1.f / (1.f + expf(-logit));
    }
}

// ---------------------------------------------------------------------------
extern "C" void kernel_launch(void* const* d_in, const int* in_sizes, int n_in,
                              void* d_out, int out_size, void* d_ws, size_t ws_size,
                              hipStream_t stream)
{
    const int*   inputs = (const int*)  d_in[0];
    const float* emb    = (const float*)d_in[1];
    const float* Wp     = (const float*)d_in[2];
    const float* bp     = (const float*)d_in[3];
    const float* Wo     = (const float*)d_in[4];
    const float* bo     = (const float*)d_in[5];
    const float* ln1_g  = (const float*)d_in[6];
    const float* ln1_b  = (const float*)d_in[7];
    const float* W1     = (const float*)d_in[8];
    const float* b1     = (const float*)d_in[9];
    const float* W2     = (const float*)d_in[10];
    const float* b2     = (const float*)d_in[11];
    const float* ln2_g  = (const float*)d_in[12];
    const float* ln2_b  = (const float*)d_in[13];
    const float* Wh     = (const float*)d_in[14];
    const float* bh     = (const float*)d_in[15];
    const float* Wf     = (const float*)d_in[16];
    const float* bf     = (const float*)d_in[17];
    float* out = (float*)d_out;

    // workspace carve (256B aligned)
    char* p = (char*)d_ws;
    ushort_t* Xt = (ushort_t*)p;       p += 33554432;   // (32,512,1024) bf16
    float* G     = (float*)p;          p += 33554432;   // (32,512,512)
    float* PE    = (float*)p;          p += 2097152;    // (1024,512)
    float* X0    = (float*)p;          p += 65536;      // (32,512)
    float* cs    = (float*)p;          p += 65536;      // (32,512)
    float* Q0    = (float*)p;          p += 65536;      // (32,512)
    float* alpha = (float*)p;          p += 1024;       // (128)
    float* r     = (float*)p;          p += 262144;     // (32,4,512)
    float* Tp    = (float*)p;          p += 262144;     // (32,4,512)
    float* gamma = (float*)p;          p += 1024;       // (128)
    float* Y1    = (float*)p;          p += 65536;      // (32,512)
    float* H1    = (float*)p;          p += 262144;     // (32,2048)
    float* H2    = (float*)p;          p += 65536;      // (32,512)
    float* X2    = (float*)p;          p += 65536;      // (32,512)

    pe_k<<<2048, 256, 0, stream>>>(PE);
    embed_k<<<dim3(8, 16, 32), 256, 0, stream>>>(inputs, emb, PE, Xt, X0);
    cs_k<<<dim3(32, 8), 256, 0, stream>>>(Xt, cs);
    gram_k<<<dim3(4, 4, 32), 256, 0, stream>>>(Xt, G);
    q0_k<<<32, 256, 0, stream>>>(X0, Wp, bp, Q0);
    r_k<<<128, 256, 0, stream>>>(Q0, Wp, bp, r, alpha);
    t_k<<<32, 256, 0, stream>>>(r, G, cs, alpha, Tp, gamma);
    hw_k<<<32, 256, 0, stream>>>(Tp, gamma, Wp, bp, Wo, bo, X0, ln1_g, ln1_b, Y1);
    tailmm_k<1><<<32, 256, 0, stream>>>(Y1, W1, b1, H1, 512, 2048);
    tailmm_k<0><<<8, 256, 0, stream>>>(H1, W2, b2, H2, 2048, 512);
    ln_rows_k<<<32, 256, 0, stream>>>(H2, Y1, 512, ln2_g, ln2_b, X2);
    head_k<<<32, 256, 0, stream>>>(X2, Wh, bh, Wf, bf, out);
}

// Round 3
// 254.887 us; speedup vs baseline: 7.1535x; 4.0546x over previous
//
#include <hip/hip_runtime.h>
#include <hip/hip_bf16.h>

typedef unsigned short ushort_t;

__device__ inline ushort_t f2bf(float x) {
    unsigned u = __float_as_uint(x);
    return (ushort_t)((u + 0x7FFFu + ((u >> 16) & 1u)) >> 16);
}

// ---------------------------------------------------------------------------
// Positional-encoding table PE[s][d], fp32 (1024 x 512)
// ---------------------------------------------------------------------------
__global__ __launch_bounds__(256) void pe_k(float* __restrict__ PE)
{
    int idx = blockIdx.x * 256 + threadIdx.x;      // < 524288
    int d = idx & 511, s = idx >> 9;
    float expo = (float)(d & ~1) * (1.0f / 512.0f);
    float ang = (float)s * exp2f(-expo * 13.287712379549449f); // 10000^-expo
    PE[idx] = (d & 1) ? cosf(ang) : sinf(ang);
}

// ---------------------------------------------------------------------------
// Embedding + PE. Writes BOTH layouts:
//   Xt[b][d][s] bf16 (for u_k: contraction over d, lanes along s)
//   Xn[b][s][d] bf16 (for tp_k: contraction over s, lanes along d)
//   X0[b][d] fp32 (s=0 row)
// ---------------------------------------------------------------------------
__global__ __launch_bounds__(256) void embed_k(
    const int* __restrict__ inp, const float* __restrict__ emb,
    const float* __restrict__ PE, ushort_t* __restrict__ Xt,
    ushort_t* __restrict__ Xn, float* __restrict__ X0)
{
    __shared__ int toks[64];
    __shared__ ushort_t tile[64][65];   // [d_local][s_local], padded
    int b = blockIdx.z, s0 = blockIdx.y * 64, d0 = blockIdx.x * 64;
    int t = threadIdx.x;
    if (t < 64) toks[t] = inp[b * 1024 + s0 + t];
    __syncthreads();

    int sl = t >> 2, c = t & 3;
    int s = s0 + sl;
    long ebase = (long)toks[sl] * 512 + d0 + c * 16;
    long pbase = (long)s * 512 + d0 + c * 16;
    ushort_t* xnrow = Xn + ((long)(b * 1024 + s)) * 512 + d0 + c * 16;
#pragma unroll
    for (int i = 0; i < 4; i++) {
        float4 e4 = *(const float4*)&emb[ebase + i * 4];
        float4 p4 = *(const float4*)&PE[pbase + i * 4];
        float v0 = e4.x + p4.x, v1 = e4.y + p4.y, v2 = e4.z + p4.z, v3 = e4.w + p4.w;
        ushort_t c0 = f2bf(v0), c1 = f2bf(v1), c2 = f2bf(v2), c3 = f2bf(v3);
        int dl = c * 16 + i * 4;
        tile[dl + 0][sl] = c0;
        tile[dl + 1][sl] = c1;
        tile[dl + 2][sl] = c2;
        tile[dl + 3][sl] = c3;
        *(uint2*)(xnrow + i * 4) = make_uint2((unsigned)c0 | ((unsigned)c1 << 16),
                                              (unsigned)c2 | ((unsigned)c3 << 16));
        if (s == 0)
            *(float4*)&X0[b * 512 + d0 + dl] = make_float4(v0, v1, v2, v3);
    }
    __syncthreads();

    int dl = t >> 2, cc = t & 3;
    unsigned pk[8];
#pragma unroll
    for (int k2 = 0; k2 < 8; k2++) {
        unsigned lo = tile[dl][cc * 16 + k2 * 2];
        unsigned hi = tile[dl][cc * 16 + k2 * 2 + 1];
        pk[k2] = lo | (hi << 16);
    }
    uint4* dst = (uint4*)(Xt + ((long)(b * 512 + d0 + dl)) * 1024 + s0 + cc * 16);
    dst[0] = make_uint4(pk[0], pk[1], pk[2], pk[3]);
    dst[1] = make_uint4(pk[4], pk[5], pk[6], pk[7]);
}

// ---------------------------------------------------------------------------
// q0 + r + alpha fused. Grid (32 b, 4 h).
// q0[f] = X0[b].Wq[h][:,f] + bq;  r[d] = sum_f q0[f] Wk[h][d][f];  alpha=q0.bk
// ---------------------------------------------------------------------------
__global__ __launch_bounds__(256) void qr_k(
    const float* __restrict__ X0, const float* __restrict__ Wp,
    const float* __restrict__ bp, float* __restrict__ r,
    float* __restrict__ alpha)
{
    __shared__ float xs[512];
    __shared__ float red[256];
    __shared__ float q0s[128];
    int b = blockIdx.x, h = blockIdx.y, t = threadIdx.x;
    xs[t] = X0[b * 512 + t];
    xs[t + 256] = X0[b * 512 + t + 256];
    __syncthreads();

    int f = t & 127, dh = t >> 7;
    const float* wq = Wp + (long)h * 512 * 384 + f;
    float acc = 0.f;
#pragma unroll 8
    for (int d = dh * 256; d < dh * 256 + 256; d++)
        acc += xs[d] * wq[(long)d * 384];
    red[t] = acc;
    __syncthreads();
    if (t < 128) q0s[t] = red[t] + red[t + 128] + bp[h * 384 + t];
    __syncthreads();
    if (t < 128) red[t] = q0s[t] * bp[h * 384 + 128 + t];
    __syncthreads();
    for (int w = 64; w >= 1; w >>= 1) {
        if (t < w) red[t] += red[t + w];
        __syncthreads();
    }
    if (t == 0) alpha[b * 4 + h] = red[0];

    const float4* q4 = (const float4*)q0s;
#pragma unroll
    for (int rep = 0; rep < 2; rep++) {
        int d = t + rep * 256;
        const float4* wr = (const float4*)(Wp + ((long)(h * 512 + d)) * 384 + 128);
        float a2 = 0.f;
#pragma unroll 8
        for (int f4 = 0; f4 < 32; f4++) {
            float4 w = wr[f4], qq = q4[f4];
            a2 += w.x * qq.x + w.y * qq.y + w.z * qq.z + w.w * qq.w;
        }
        r[((long)(b * 4 + h)) * 512 + d] = a2;
    }
}

// ---------------------------------------------------------------------------
// u partials: Up[b][dc][h][s] = sum_{d in chunk} Xt[b][d][s] * r[b,h,d]
// Grid (32 b, 4 dc). Lanes along s (coalesced uint2), r in LDS (broadcast).
// ---------------------------------------------------------------------------
__global__ __launch_bounds__(256) void u_k(
    const ushort_t* __restrict__ Xt, const float* __restrict__ r,
    float* __restrict__ Up)
{
    __shared__ float rs[512];
    int b = blockIdx.x, dc = blockIdx.y, t = threadIdx.x;
#pragma unroll
    for (int i = 0; i < 2; i++) {
        int ii = t + i * 256;
        int h = ii >> 7, dl = ii & 127;
        rs[h * 128 + dl] = r[((long)(b * 4 + h)) * 512 + dc * 128 + dl];
    }
    __syncthreads();
    const ushort_t* Xb = Xt + (long)b * 524288 + (long)(dc * 128) * 1024 + 4 * t;
    float acc[4][4] = {};
#pragma unroll 4
    for (int dl = 0; dl < 128; dl++) {
        uint2 xv = *(const uint2*)(Xb + (long)dl * 1024);
        float x0 = __uint_as_float(xv.x << 16);
        float x1 = __uint_as_float(xv.x & 0xffff0000u);
        float x2 = __uint_as_float(xv.y << 16);
        float x3 = __uint_as_float(xv.y & 0xffff0000u);
#pragma unroll
        for (int h = 0; h < 4; h++) {
            float rr = rs[h * 128 + dl];
            acc[h][0] += rr * x0; acc[h][1] += rr * x1;
            acc[h][2] += rr * x2; acc[h][3] += rr * x3;
        }
    }
#pragma unroll
    for (int h = 0; h < 4; h++)
        *(float4*)&Up[((long)((b * 4 + dc) * 4 + h)) * 1024 + 4 * t] =
            make_float4(acc[h][0], acc[h][1], acc[h][2], acc[h][3]);
}

// ---------------------------------------------------------------------------
// u = sum_dc Up + alpha;  gamma[b,h] = sum_s u.  Grid (32 b, 4 h).
// ---------------------------------------------------------------------------
__global__ __launch_bounds__(256) void ured_k(
    const float* __restrict__ Up, const float* __restrict__ alpha,
    float* __restrict__ u, float* __restrict__ gamma)
{
    __shared__ float sd[4];
    int b = blockIdx.x, h = blockIdx.y, t = threadIdx.x;
    float al = alpha[b * 4 + h];
    float4 s = make_float4(al, al, al, al);
#pragma unroll
    for (int dc = 0; dc < 4; dc++) {
        float4 v = *(const float4*)&Up[((long)((b * 4 + dc) * 4 + h)) * 1024 + 4 * t];
        s.x += v.x; s.y += v.y; s.z += v.z; s.w += v.w;
    }
    *(float4*)&u[((long)(b * 4 + h)) * 1024 + 4 * t] = s;
    float p = s.x + s.y + s.z + s.w;
#pragma unroll
    for (int off = 32; off; off >>= 1) p += __shfl_down(p, off);
    if ((t & 63) == 0) sd[t >> 6] = p;
    __syncthreads();
    if (t == 0) gamma[b * 4 + h] = sd[0] + sd[1] + sd[2] + sd[3];
}

// ---------------------------------------------------------------------------
// t' partials: Tpp[b][sc][h][d] = sum_{s in chunk} Xn[b][s][d] * u[b,h,s]
// Grid (32 b, 4 sc). Lanes along d (coalesced), u in LDS (broadcast).
// ---------------------------------------------------------------------------
__global__ __launch_bounds__(256) void tp_k(
    const ushort_t* __restrict__ Xn, const float* __restrict__ u,
    float* __restrict__ Tpp)
{
    __shared__ float uu[1024];
    int b = blockIdx.x, sc = blockIdx.y, t = threadIdx.x;
    ((float4*)uu)[t] =
        ((const float4*)(u + (long)b * 4096 + (long)(t >> 6) * 1024 + sc * 256))[t & 63];
    __syncthreads();
    const ushort_t* Xp = Xn + (long)b * 524288 + (long)(sc * 256) * 512 + 2 * t;
    float acc[4][2] = {};
#pragma unroll 8
    for (int sl = 0; sl < 256; sl++) {
        unsigned xv = *(const unsigned*)(Xp + (long)sl * 512);
        float x0 = __uint_as_float(xv << 16);
        float x1 = __uint_as_float(xv & 0xffff0000u);
#pragma unroll
        for (int h = 0; h < 4; h++) {
            float uv = uu[h * 256 + sl];
            acc[h][0] += uv * x0;
            acc[h][1] += uv * x1;
        }
    }
#pragma unroll
    for (int h = 0; h < 4; h++)
        *(float2*)&Tpp[((long)((b * 4 + sc) * 4 + h)) * 512 + 2 * t] =
            make_float2(acc[h][0], acc[h][1]);
}

// ---------------------------------------------------------------------------
// c0[b, h*128+e] = scale*(sum_d t'[h][d] Wv[h][d][e] + gamma[h] bv[h][e])
// Grid (32 b, 8 jt). Sums the 4 sc-partials of t' on load.
// ---------------------------------------------------------------------------
__global__ __launch_bounds__(256) void att1_k(
    const float* __restrict__ Tpp, const float* __restrict__ gamma,
    const float* __restrict__ Wp, const float* __restrict__ bp,
    float* __restrict__ C0)
{
    __shared__ float tps[512];
    __shared__ float red[256];
    int b = blockIdx.x, jt = blockIdx.y, t = threadIdx.x;
    int h = jt >> 1, e0 = (jt & 1) * 64;
#pragma unroll
    for (int i = 0; i < 2; i++) {
        int d = t + i * 256;
        float v = 0.f;
#pragma unroll
        for (int sc = 0; sc < 4; sc++)
            v += Tpp[((long)((b * 4 + sc) * 4 + h)) * 512 + d];
        tps[d] = v;
    }
    __syncthreads();
    int e = e0 + (t & 63), rg = t >> 6;
    const float* wv = Wp + (long)h * 512 * 384 + 256 + e;
    float acc = 0.f;
#pragma unroll 8
    for (int d = rg * 128; d < rg * 128 + 128; d++)
        acc += tps[d] * wv[(long)d * 384];
    red[t] = acc;
    __syncthreads();
    if (t < 64) {
        float sum = red[t] + red[t + 64] + red[t + 128] + red[t + 192];
        float c = 0.03125f * (sum + gamma[b * 4 + h] * bp[h * 384 + 256 + e0 + t]);
        C0[b * 512 + h * 128 + e0 + t] = c;
    }
}

// ---------------------------------------------------------------------------
// ATT0 = c0 @ Wo + bo.  Grid (32 b, 8 jt).
// ---------------------------------------------------------------------------
__global__ __launch_bounds__(256) void att2_k(
    const float* __restrict__ C0, const float* __restrict__ Wo,
    const float* __restrict__ bo, float* __restrict__ ATT0)
{
    __shared__ float c0s[512];
    __shared__ float red[256];
    int b = blockIdx.x, jt = blockIdx.y, t = threadIdx.x;
    c0s[t] = C0[b * 512 + t];
    c0s[t + 256] = C0[b * 512 + t + 256];
    __syncthreads();
    int j = jt * 64 + (t & 63), rg = t >> 6;
    float acc = 0.f;
#pragma unroll 8
    for (int d = rg * 128; d < rg * 128 + 128; d++)
        acc += c0s[d] * Wo[(long)d * 512 + j];
    red[t] = acc;
    __syncthreads();
    if (t < 64) {
        int jj = jt * 64 + t;
        ATT0[b * 512 + jj] = red[t] + red[t + 64] + red[t + 128] + red[t + 192] + bo[jj];
    }
}

// ---------------------------------------------------------------------------
// Row LayerNorm over D=512 with residual:  out = LN(in + res)*g + b
// ---------------------------------------------------------------------------
__global__ __launch_bounds__(256) void ln_rows_k(
    const float* __restrict__ in, const float* __restrict__ res,
    const float* __restrict__ g, const float* __restrict__ bta,
    float* __restrict__ out)
{
    int b = blockIdx.x;
    int t = threadIdx.x;
    float a0 = in[b * 512 + t] + res[b * 512 + t];
    float a1 = in[b * 512 + t + 256] + res[b * 512 + t + 256];

    __shared__ float sd[8];
    float s = a0 + a1;
#pragma unroll
    for (int off = 32; off; off >>= 1) s += __shfl_down(s, off);
    if ((t & 63) == 0) sd[t >> 6] = s;
    __syncthreads();
    float mean = (sd[0] + sd[1] + sd[2] + sd[3]) * (1.0f / 512.0f);

    float d0 = a0 - mean, d1 = a1 - mean;
    float v = d0 * d0 + d1 * d1;
#pragma unroll
    for (int off = 32; off; off >>= 1) v += __shfl_down(v, off);
    if ((t & 63) == 0) sd[4 + (t >> 6)] = v;
    __syncthreads();
    float var = (sd[4] + sd[5] + sd[6] + sd[7]) * (1.0f / 512.0f);
    float rstd = rsqrtf(var + 0.001f);

    out[b * 512 + t] = d0 * rstd * g[t] + bta[t];
    out[b * 512 + t + 256] = d1 * rstd * g[t + 256] + bta[t + 256];
}

// ---------------------------------------------------------------------------
// FFN1 partials: Hp1[ks][32][2048] = Y1[:, kchunk] @ W1[kchunk, :]
// Grid (32 jt, 4 ks). W1 read exactly once grid-wide.
// ---------------------------------------------------------------------------
__global__ __launch_bounds__(256) void ffn1_k(
    const float* __restrict__ Y1, const float* __restrict__ W1,
    float* __restrict__ Hp1)
{
    __shared__ float at[32][128];
    int jt = blockIdx.x, ks = blockIdx.y, t = threadIdx.x;
#pragma unroll
    for (int i = 0; i < 4; i++) {
        int idx = t + i * 256;
        int row = idx >> 5, f4 = idx & 31;
        ((float4*)at)[idx] = ((const float4*)(Y1 + (long)row * 512 + ks * 128))[f4];
    }
    __syncthreads();
    int j = jt * 64 + (t & 63), rg = t >> 6;
    float acc[8] = {};
    const float* w = W1 + (long)(ks * 128) * 2048 + j;
#pragma unroll 4
    for (int k = 0; k < 128; k++) {
        float wv = w[(long)k * 2048];
#pragma unroll
        for (int rr = 0; rr < 8; rr++)
            acc[rr] += at[rg * 8 + rr][k] * wv;
    }
#pragma unroll
    for (int rr = 0; rr < 8; rr++)
        Hp1[((long)(ks * 32 + rg * 8 + rr)) * 2048 + j] = acc[rr];
}

// ---------------------------------------------------------------------------
// H1 = relu(sum_ks Hp1 + b1)
// ---------------------------------------------------------------------------
__global__ __launch_bounds__(256) void ffn1r_k(
    const float* __restrict__ Hp1, const float* __restrict__ b1,
    float* __restrict__ H1)
{
    int idx = blockIdx.x * 256 + threadIdx.x;   // < 16384 (float4 units)
    int gi = idx * 4;
    int j = gi & 2047;
    float4 v = *(const float4*)&b1[j];
#pragma unroll
    for (int ks = 0; ks < 4; ks++) {
        float4 pv = *(const float4*)&Hp1[(long)ks * 65536 + gi];
        v.x += pv.x; v.y += pv.y; v.z += pv.z; v.w += pv.w;
    }
    v.x = fmaxf(v.x, 0.f); v.y = fmaxf(v.y, 0.f);
    v.z = fmaxf(v.z, 0.f); v.w = fmaxf(v.w, 0.f);
    *(float4*)&H1[gi] = v;
}

// ---------------------------------------------------------------------------
// FFN2 partials: Hp2[ks][32][512] = H1[:, kchunk] @ W2[kchunk, :]
// Grid (8 jt, 16 ks).
// ---------------------------------------------------------------------------
__global__ __launch_bounds__(256) void ffn2_k(
    const float* __restrict__ H1, const float* __restrict__ W2,
    float* __restrict__ Hp2)
{
    __shared__ float at[32][128];
    int jt = blockIdx.x, ks = blockIdx.y, t = threadIdx.x;
#pragma unroll
    for (int i = 0; i < 4; i++) {
        int idx = t + i * 256;
        int row = idx >> 5, f4 = idx & 31;
        ((float4*)at)[idx] = ((const float4*)(H1 + (long)row * 2048 + ks * 128))[f4];
    }
    __syncthreads();
    int j = jt * 64 + (t & 63), rg = t >> 6;
    float acc[8] = {};
    const float* w = W2 + (long)(ks * 128) * 512 + j;
#pragma unroll 4
    for (int k = 0; k < 128; k++) {
        float wv = w[(long)k * 512];
#pragma unroll
        for (int rr = 0; rr < 8; rr++)
            acc[rr] += at[rg * 8 + rr][k] * wv;
    }
#pragma unroll
    for (int rr = 0; rr < 8; rr++)
        Hp2[((long)(ks * 32 + rg * 8 + rr)) * 512 + j] = acc[rr];
}

// ---------------------------------------------------------------------------
// X2 = LN(sum_ks Hp2 + b2 + Y1).  Grid 32.
// ---------------------------------------------------------------------------
__global__ __launch_bounds__(256) void ln2_k(
    const float* __restrict__ Hp2, const float* __restrict__ b2,
    const float* __restrict__ Y1, const float* __restrict__ g,
    const float* __restrict__ bta, float* __restrict__ X2)
{
    __shared__ float sd[8];
    int b = blockIdx.x, t = threadIdx.x;
    float a[2];
#pragma unroll
    for (int rep = 0; rep < 2; rep++) {
        int j = t + rep * 256;
        float v = b2[j] + Y1[b * 512 + j];
#pragma unroll
        for (int ks = 0; ks < 16; ks++)
            v += Hp2[((long)(ks * 32 + b)) * 512 + j];
        a[rep] = v;
    }
    float s = a[0] + a[1];
#pragma unroll
    for (int off = 32; off; off >>= 1) s += __shfl_down(s, off);
    if ((t & 63) == 0) sd[t >> 6] = s;
    __syncthreads();
    float mean = (sd[0] + sd[1] + sd[2] + sd[3]) * (1.0f / 512.0f);
    float d0 = a[0] - mean, d1 = a[1] - mean;
    float v2 = d0 * d0 + d1 * d1;
#pragma unroll
    for (int off = 32; off; off >>= 1) v2 += __shfl_down(v2, off);
    if ((t & 63) == 0) sd[4 + (t >> 6)] = v2;
    __syncthreads();
    float var = (sd[4] + sd[5] + sd[6] + sd[7]) * (1.0f / 512.0f);
    float rstd = rsqrtf(var + 0.001f);
    X2[b * 512 + t] = d0 * rstd * g[t] + bta[t];
    X2[b * 512 + t + 256] = d1 * rstd * g[t + 256] + bta[t + 256];
}

// ---------------------------------------------------------------------------
// Head partials: Pl[b][jt] = sum_{j in tile} relu(X2[b].Wh[:,j]+bh[j])*Wf[j]
// Grid (32 b, 8 jt).
// ---------------------------------------------------------------------------
__global__ __launch_bounds__(256) void headp_k(
    const float* __restrict__ X2, const float* __restrict__ Wh,
    const float* __restrict__ bh, const float* __restrict__ Wf,
    float* __restrict__ Pl)
{
    __shared__ float xs[512];
    __shared__ float red[256];
    int b = blockIdx.x, jt = blockIdx.y, t = threadIdx.x;
    xs[t] = X2[b * 512 + t];
    xs[t + 256] = X2[b * 512 + t + 256];
    __syncthreads();
    int j = jt * 64 + (t & 63), rg = t >> 6;
    const float* w = Wh + j;
    float acc = 0.f;
#pragma unroll 8
    for (int d = rg * 128; d < rg * 128 + 128; d++)
        acc += xs[d] * w[(long)d * 512];
    red[t] = acc;
    __syncthreads();
    if (t < 64) {
        int jj = jt * 64 + t;
        float hid = red[t] + red[t + 64] + red[t + 128] + red[t + 192] + bh[jj];
        hid = fmaxf(hid, 0.f);
        float p = hid * Wf[jj];
#pragma unroll
        for (int off = 32; off; off >>= 1) p += __shfl_down(p, off);
        if (t == 0) Pl[b * 8 + jt] = p;
    }
}

__global__ __launch_bounds__(64) void final_k(
    const float* __restrict__ Pl, const float* __restrict__ bf,
    float* __restrict__ out)
{
    int t = threadIdx.x;
    if (t < 32) {
        float logit = bf[0];
#pragma unroll
        for (int jt = 0; jt < 8; jt++) logit += Pl[t * 8 + jt];
        out[t] = logit;
        out[32 + t] = 1.f / (1.f + expf(-logit));
    }
}

// ---------------------------------------------------------------------------
extern "C" void kernel_launch(void* const* d_in, const int* in_sizes, int n_in,
                              void* d_out, int out_size, void* d_ws, size_t ws_size,
                              hipStream_t stream)
{
    const int*   inputs = (const int*)  d_in[0];
    const float* emb    = (const float*)d_in[1];
    const float* Wp     = (const float*)d_in[2];
    const float* bp     = (const float*)d_in[3];
    const float* Wo     = (const float*)d_in[4];
    const float* bo     = (const float*)d_in[5];
    const float* ln1_g  = (const float*)d_in[6];
    const float* ln1_b  = (const float*)d_in[7];
    const float* W1     = (const float*)d_in[8];
    const float* b1     = (const float*)d_in[9];
    const float* W2     = (const float*)d_in[10];
    const float* b2     = (const float*)d_in[11];
    const float* ln2_g  = (const float*)d_in[12];
    const float* ln2_b  = (const float*)d_in[13];
    const float* Wh     = (const float*)d_in[14];
    const float* bh     = (const float*)d_in[15];
    const float* Wf     = (const float*)d_in[16];
    const float* bf     = (const float*)d_in[17];
    float* out = (float*)d_out;

    char* p = (char*)d_ws;
    ushort_t* Xt  = (ushort_t*)p;  p += 33554432;   // (32,512,1024) bf16
    ushort_t* Xn  = (ushort_t*)p;  p += 33554432;   // (32,1024,512) bf16
    float* PE     = (float*)p;     p += 2097152;    // (1024,512)
    float* X0     = (float*)p;     p += 65536;      // (32,512)
    float* r      = (float*)p;     p += 262144;     // (32,4,512)
    float* alpha  = (float*)p;     p += 1024;       // (128)
    float* Up     = (float*)p;     p += 2097152;    // (32,4,4,1024)
    float* u      = (float*)p;     p += 524288;     // (32,4,1024)
    float* gamma  = (float*)p;     p += 1024;       // (128)
    float* Tpp    = (float*)p;     p += 1048576;    // (32,4,4,512)
    float* C0     = (float*)p;     p += 65536;      // (32,512)
    float* ATT0   = (float*)p;     p += 65536;      // (32,512)
    float* Y1     = (float*)p;     p += 65536;      // (32,512)
    float* Hp1    = (float*)p;     p += 1048576;    // (4,32,2048)
    float* H1     = (float*)p;     p += 262144;     // (32,2048)
    float* Hp2    = (float*)p;     p += 1048576;    // (16,32,512)
    float* X2     = (float*)p;     p += 65536;      // (32,512)
    float* Pl     = (float*)p;     p += 1024;       // (32,8)

    pe_k<<<2048, 256, 0, stream>>>(PE);
    embed_k<<<dim3(8, 16, 32), 256, 0, stream>>>(inputs, emb, PE, Xt, Xn, X0);
    qr_k<<<dim3(32, 4), 256, 0, stream>>>(X0, Wp, bp, r, alpha);
    u_k<<<dim3(32, 4), 256, 0, stream>>>(Xt, r, Up);
    ured_k<<<dim3(32, 4), 256, 0, stream>>>(Up, alpha, u, gamma);
    tp_k<<<dim3(32, 4), 256, 0, stream>>>(Xn, u, Tpp);
    att1_k<<<dim3(32, 8), 256, 0, stream>>>(Tpp, gamma, Wp, bp, C0);
    att2_k<<<dim3(32, 8), 256, 0, stream>>>(C0, Wo, bo, ATT0);
    ln_rows_k<<<32, 256, 0, stream>>>(ATT0, X0, ln1_g, ln1_b, Y1);
    ffn1_k<<<dim3(32, 4), 256, 0, stream>>>(Y1, W1, Hp1);
    ffn1r_k<<<64, 256, 0, stream>>>(Hp1, b1, H1);
    ffn2_k<<<dim3(8, 16), 256, 0, stream>>>(H1, W2, Hp2);
    ln2_k<<<32, 256, 0, stream>>>(Hp2, b2, Y1, ln2_g, ln2_b, X2);
    headp_k<<<dim3(32, 8), 256, 0, stream>>>(X2, Wh, bh, Wf, Pl);
    final_k<<<1, 64, 0, stream>>>(Pl, bf, out);
}